// Round 3
// baseline (201.296 us; speedup 1.0000x reference)
//
#include <hip/hip_runtime.h>
#include <stdint.h>

// Problem constants
#define B_    16
#define C_    80
#define H_    128
#define W_    128
#define HW_   16384        // H_*W_
#define NBINS 1024
#define BIN_BASE 0x3C00u   // float bits>>16 lower bound for scores > ~0.0078
#define SORTN 1024
// Eager pre-filter: 0.9992675781f. Per-batch candidates ~960 (>=100 w/ 27-sigma
// margin on uniform data); per-channel ~12 (cap 64 untouchable). Any violation
// -> exact fallback.
#define F1_BITS 0x3F7FD000u
#define CHCAP 64u          // per-channel candidate cap. MUST be 64 (>>6 / &63).
#define PADTOT (C_ * (int)CHCAP)   // 5120 padded slots per batch
#define FSHIFT 5           // fine-hist shift: bin = (bits - F1_BITS) >> 5
#define FBINS 512          // logical 384 used ((0x3000>>5)=384); padded to 512
#define LSCAP 2048         // LDS stash cap (mean 960, 34-sigma margin)

// ws layout (bytes):
//   chCnt : B_*C_*4 = 5120  @ 0          (written unconditionally per block)
//   done  : B_*4 = 64       @ 5120       (MUST be zeroed per iteration ->
//                                         hipMemsetAsync in kernel_launch;
//                                         workspace is re-poisoned each iter)
//   buf   : B_*C_*CHCAP*8 = 640KB @ 8192
#define WS_CC_OFF   0
#define WS_DONE_OFF 5120
#define WS_BUF_OFF  8192

// Horizontal 3-max (incl. center) of a 4-wide strip, halo via wave shuffle.
// (fallback path only)
__device__ __forceinline__ float4 hmax3(float4 v, int srcL, int srcR, int tx) {
    float lft = __shfl(v.w, srcL);
    float rgt = __shfl(v.x, srcR);
    if (tx == 0)  lft = -1.f;
    if (tx == 31) rgt = -1.f;
    float4 h;
    h.x = fmaxf(v.x, fmaxf(lft, v.y));
    h.y = fmaxf(v.y, fmaxf(v.x, v.z));
    h.z = fmaxf(v.z, fmaxf(v.y, v.w));
    h.w = fmaxf(v.w, fmaxf(v.z, rgt));
    return h;
}

// Wave-aggregated LDS histogram add (degenerate same-bin case -> 1 atomic/wave).
__device__ __forceinline__ void hist_add(unsigned* lh, bool valid, unsigned bin,
                                         int lane) {
    unsigned long long vm = __ballot(valid);
    if (vm == 0ull) return;
    int leader = __ffsll((unsigned long long)vm) - 1;
    unsigned lbin = __shfl(bin, leader);
    unsigned long long sm = __ballot(valid && bin == lbin);
    if (sm == vm) {
        if (lane == leader) atomicAdd(&lh[lbin], (unsigned)__popcll(vm));
    } else if (valid) {
        atomicAdd(&lh[bin], 1u);
    }
}

__device__ __forceinline__ unsigned long long make_key(unsigned bits, int c,
                                                       int y, int x) {
    unsigned idx = ((unsigned)c << 14) | ((unsigned)y << 7) | (unsigned)x;
    return ((unsigned long long)bits << 32) |
           (unsigned long long)(0xFFFFFFFFu - idx);
}

// Rolling 3-row NMS scan of one 128x128 channel (fallback path only).
// emit(f, m3x3, y, x) invoked for ALL pixels (safe for wave-ballot inside).
template <typename EmitFn>
__device__ __forceinline__ void nms_scan_channel(const float4* __restrict__ img,
                                                 EmitFn emit) {
    int tx = threadIdx.x & 31;
    int ty = threadIdx.x >> 5;
    int y0 = ty << 4;
    int lane = threadIdx.x & 63;
    int srcL = (lane > 0) ? lane - 1 : 0;
    int srcR = (lane < 63) ? lane + 1 : 63;
    const float4 neg1 = make_float4(-1.f, -1.f, -1.f, -1.f);

    float4 r0 = (y0 > 0) ? img[(y0 - 1) * 32 + tx] : neg1;
    float4 hprev = hmax3(r0, srcL, srcR, tx);
    float4 vcur = img[y0 * 32 + tx];
    float4 hcur = hmax3(vcur, srcL, srcR, tx);

    #pragma unroll 4
    for (int i = 0; i < 16; i++) {
        int y = y0 + i;
        float4 vn = (y + 1 < H_) ? img[(y + 1) * 32 + tx] : neg1;
        float4 hnext = hmax3(vn, srcL, srcR, tx);
        float mm[4];
        mm[0] = fmaxf(hprev.x, fmaxf(hcur.x, hnext.x));
        mm[1] = fmaxf(hprev.y, fmaxf(hcur.y, hnext.y));
        mm[2] = fmaxf(hprev.z, fmaxf(hcur.z, hnext.z));
        mm[3] = fmaxf(hprev.w, fmaxf(hcur.w, hnext.w));
        float vv[4] = {vcur.x, vcur.y, vcur.z, vcur.w};
        #pragma unroll
        for (int j = 0; j < 4; j++) emit(vv[j], mm[j], y, tx * 4 + j);
        hprev = hcur; hcur = hnext; vcur = vn;
    }
}

// 1024-bin suffix threshold (fallback): T = smallest bin with suffix >= 100
// (0 if total < 100); cntHi = count strictly above T.
__device__ __forceinline__ void find_suffix_thresh(const unsigned* __restrict__ h,
                                                   unsigned* __restrict__ seg,
                                                   unsigned* Tout,
                                                   unsigned* cntHiOut) {
    __syncthreads();
    int t = threadIdx.x;
    int base = t * 4;
    unsigned h0 = h[base], h1 = h[base + 1], h2 = h[base + 2], h3 = h[base + 3];
    seg[t] = h0 + h1 + h2 + h3;
    __syncthreads();
    for (int d = 1; d < 256; d <<= 1) {
        unsigned add = (t + d < 256) ? seg[t + d] : 0u;
        __syncthreads();
        seg[t] += add;
        __syncthreads();
    }
    unsigned mySuf = seg[t];
    unsigned nextSuf = (t < 255) ? seg[t + 1] : 0u;
    if (t == 0 && mySuf < 100u) { *Tout = 0u; *cntHiOut = mySuf - h0; }
    if (mySuf >= 100u && nextSuf < 100u) {
        unsigned cum = nextSuf;
        unsigned hv[4] = {h0, h1, h2, h3};
        for (int i = 3; i >= 0; i--) {
            cum += hv[i];
            if (cum >= 100u) { *Tout = (unsigned)(base + i); *cntHiOut = cum - hv[i]; break; }
        }
    }
    __syncthreads();
}

// decode one key into output row r of batch b
__device__ __forceinline__ void decode_write(unsigned long long key, unsigned r,
                                             int b,
                                             const float* __restrict__ offset,
                                             const float* __restrict__ wh,
                                             float* __restrict__ out) {
    unsigned bits = (unsigned)(key >> 32);
    unsigned idx  = 0xFFFFFFFFu - (unsigned)(key & 0xFFFFFFFFu);
    int cc = (int)(idx >> 14);
    int sp = (int)(idx & 16383u);
    int y  = sp >> 7;
    int x  = sp & 127;
    const float* offb = offset + (size_t)b * 2 * HW_;
    const float* whb  = wh + (size_t)b * 2 * HW_;
    float ox = offb[sp], oy = offb[HW_ + sp];
    float wwv = whb[sp], hh = whb[HW_ + sp];
    float cx = (float)x + ox;
    float cy = (float)y + oy;
    int o = b * 100 + (int)r;
    out[o]        = (float)cc;
    out[1600 + o] = __uint_as_float(bits);
    float* bb = out + 3200 + o * 4;
    bb[0] = (cx - wwv * 0.5f) * 4.0f;
    bb[1] = (cy - hh * 0.5f) * 4.0f;
    bb[2] = (cx + wwv * 0.5f) * 4.0f;
    bb[3] = (cy + hh * 0.5f) * 4.0f;
}

// ---------------------------------------------------------------------------
// FUSED kernel: per-channel eager NMS scan (phase A) + last-block-per-batch
// top-100 (phase B). One block per (b,c); the 80th block to finish a batch
// (device-scope atomic on done[b]) runs the batch's top-k inline. This removes
// the K1->K2 full-grid drain: batch b's top-k starts when ITS 80 channels are
// done, not when all 1280 blocks are.
//
// Phase A: 16-deep explicit load pipeline (HBM-throughput-bound), integer
// pre-filter -> 16-bit row mask, divergent rare path (~12 survivors / 16384
// pixels) re-reads the 3x3 neighborhood from L1.
//
// Phase B: identical logic to the previous proven topk_decode (fast path:
// fine-hist + LDS stash + suffix scan + compact; guards -> exact 3-pass
// fallback; tail: rank-selection + fused decode).
//
// Cross-XCD visibility: writer side __syncthreads() -> __threadfence() ->
// atomicAdd(done) release; reader side observes count==C_-1 -> __threadfence()
// acquire -> reads buf/chCnt. Standard HIP inter-block pattern.
//
// LDS ~32.1 KB -> 5 blocks/CU, all 1280 blocks co-resident (not relied upon
// for correctness).
// ---------------------------------------------------------------------------
__global__ __launch_bounds__(256) void nms_topk_fused(
        const float* __restrict__ hm,
        unsigned* __restrict__ chCnt,
        unsigned long long* __restrict__ buf,
        unsigned* __restrict__ done,
        const float* __restrict__ offset,
        const float* __restrict__ wh,
        float* __restrict__ out) {
    __shared__ unsigned lcnt;
    __shared__ unsigned lastFlag;
    // phase-B LDS (untouched during phase A)
    __shared__ unsigned long long ls[LSCAP];  // 16 KB stash
    __shared__ unsigned long long s[SORTN];   // 8 KB select buffer
    __shared__ unsigned lh[NBINS];            // fast: [0..FBINS); fb: all 1024
    __shared__ unsigned seg[256];
    __shared__ unsigned shC[256];
    __shared__ unsigned sufC[256];
    __shared__ unsigned scnt[C_];
    __shared__ unsigned rawTotS, ovfS, stashCnt, U2s, takeS, T1s, cntHiS, Us, cntL;

    if (threadIdx.x == 0) lcnt = 0u;
    __syncthreads();

    int bc = blockIdx.x;         // b*C_ + c
    int c  = bc % C_;
    int b  = bc / C_;
    int t  = threadIdx.x;
    int tx = t & 31;
    int ty = t >> 5;
    int y0 = ty << 4;
    int lane = t & 63;
    const float* base = hm + (size_t)bc * HW_;
    const float4* img = (const float4*)base;
    unsigned long long* myseg = buf + (size_t)bc * CHCAP;

    // ---- phase A: issue all 16 independent row loads, integer pre-filter,
    // rare-path 3x3 check.
    float4 R[16];
    #pragma unroll
    for (int k = 0; k < 16; k++) R[k] = img[(y0 + k) * 32 + tx];

    unsigned mask = 0u;
    #pragma unroll
    for (int k = 0; k < 16; k++) {
        unsigned a = __float_as_uint(R[k].x), bb2 = __float_as_uint(R[k].y);
        unsigned cc2 = __float_as_uint(R[k].z), d = __float_as_uint(R[k].w);
        unsigned m0 = a > bb2 ? a : bb2;
        unsigned m1 = cc2 > d ? cc2 : d;
        unsigned mx = m0 > m1 ? m0 : m1;
        mask |= (mx >= F1_BITS ? 1u : 0u) << k;
    }

    while (mask) {
        int k = __ffs(mask) - 1;
        mask &= mask - 1u;
        int y = y0 + k;
        float4 v = img[y * 32 + tx];       // L1-hot reload (no R[k] runtime idx)
        float vv[4] = {v.x, v.y, v.z, v.w};
        #pragma unroll
        for (int j = 0; j < 4; j++) {
            float f = vv[j];
            if (__float_as_uint(f) < F1_BITS) continue;
            int x = tx * 4 + j;
            bool xm = (x > 0), xp = (x < W_ - 1);
            float m = -1.f;
            if (y > 0) {
                const float* r = base + (y - 1) * W_;
                if (xm) m = fmaxf(m, r[x - 1]);
                m = fmaxf(m, r[x]);
                if (xp) m = fmaxf(m, r[x + 1]);
            }
            {
                const float* r = base + y * W_;
                if (xm) m = fmaxf(m, r[x - 1]);
                if (xp) m = fmaxf(m, r[x + 1]);
            }
            if (y < H_ - 1) {
                const float* r = base + (y + 1) * W_;
                if (xm) m = fmaxf(m, r[x - 1]);
                m = fmaxf(m, r[x]);
                if (xp) m = fmaxf(m, r[x + 1]);
            }
            if (f >= m) {
                unsigned pos = atomicAdd(&lcnt, 1u);
                if (pos < CHCAP)
                    myseg[pos] = make_key(__float_as_uint(f), c, y, x);
            }
        }
    }

    __syncthreads();
    // ---- release + signal; detect last block of this batch
    if (t == 0) {
        chCnt[bc] = lcnt;
        __threadfence();                       // release buf/chCnt writes
        unsigned old = atomicAdd(&done[b], 1u);
        lastFlag = (old == (unsigned)(C_ - 1)) ? 1u : 0u;
    }
    __syncthreads();
    if (lastFlag == 0u) return;
    __threadfence();                           // acquire other blocks' writes

    // ---- phase B: top-100 for batch b (identical logic to proven topk_decode)
    if (t == 0) { rawTotS = 0u; ovfS = 0u; stashCnt = 0u; cntL = 0u;
                  U2s = 0u; takeS = 0u; T1s = 0u; cntHiS = 0u; Us = 0u; }
    lh[t] = 0u; lh[t + 256] = 0u;             // fast path uses FBINS=512
    __syncthreads();
    if (t < C_) {
        unsigned r = chCnt[b * C_ + t];
        atomicAdd(&rawTotS, r);
        if (r > CHCAP) atomicOr(&ovfS, 1u);
        scnt[t] = r > CHCAP ? CHCAP : r;
    }
    __syncthreads();
    bool fb = (rawTotS < 100u) || (ovfS != 0u);

    const unsigned long long* bufb = buf + (size_t)b * C_ * CHCAP;
    unsigned n2 = 0u;

    if (!fb) {
        // single global pass: fine hist + LDS stash
        #pragma unroll 4
        for (unsigned i0 = 0; i0 < (unsigned)PADTOT; i0 += 256) {
            unsigned i  = i0 + t;
            unsigned sg = i >> 6;              // CHCAP == 64
            unsigned off = i & (CHCAP - 1u);
            bool valid = off < scnt[sg];
            unsigned long long key = 0ull;
            if (valid) {
                key = bufb[i];
                unsigned bin = ((unsigned)(key >> 32) - F1_BITS) >> FSHIFT;
                if (bin > FBINS - 1u) bin = FBINS - 1u;
                atomicAdd(&lh[bin], 1u);
            }
            unsigned long long m = __ballot(valid);
            if (m != 0ull) {
                int leader = __ffsll((unsigned long long)m) - 1;
                unsigned wcnt = (unsigned)__popcll(m);
                unsigned wbase = 0u;
                if (lane == leader) wbase = atomicAdd(&stashCnt, wcnt);
                wbase = __shfl(wbase, leader);
                if (valid) {
                    unsigned pos = wbase + (unsigned)__popcll(m & ((1ull << lane) - 1ull));
                    if (pos < LSCAP) ls[pos] = key;
                }
            }
        }
        __syncthreads();
        if (stashCnt > LSCAP) fb = true;
        // suffix scan over FBINS (2 bins/thread) -> U2, exact takeCnt
        unsigned g0 = lh[t * 2], g1 = lh[t * 2 + 1];
        seg[t] = g0 + g1;
        __syncthreads();
        for (int d = 1; d < 256; d <<= 1) {
            unsigned add = (t + d < 256) ? seg[t + d] : 0u;
            __syncthreads();
            seg[t] += add;
            __syncthreads();
        }
        unsigned mySuf = seg[t];
        unsigned nextSuf = (t < 255) ? seg[t + 1] : 0u;
        if (mySuf >= 100u && nextSuf < 100u) {   // exists since rawTot >= 100
            unsigned cum1 = nextSuf + g1;
            if (cum1 >= 100u) { U2s = (unsigned)(t * 2 + 1); takeS = cum1; }
            else              { U2s = (unsigned)(t * 2);     takeS = cum1 + g0; }
        }
        __syncthreads();
        unsigned U2 = U2s, takeCnt = takeS;
        if (takeCnt > SORTN) fb = true;          // massive tie block
        if (!fb) {
            // compact from LDS stash (keys with fine-bin >= U2)
            unsigned sn = stashCnt;
            for (unsigned i0 = 0; i0 < sn; i0 += 256) {
                unsigned i = i0 + t;
                bool valid = (i < sn);
                unsigned long long key = valid ? ls[i] : 0ull;
                bool take = false;
                if (valid) {
                    unsigned bin = ((unsigned)(key >> 32) - F1_BITS) >> FSHIFT;
                    if (bin > FBINS - 1u) bin = FBINS - 1u;
                    take = (bin >= U2);
                }
                unsigned long long m = __ballot(take);
                if (m != 0ull) {
                    int leader = __ffsll((unsigned long long)m) - 1;
                    unsigned wcnt = (unsigned)__popcll(m);
                    unsigned wbase = 0u;
                    if (lane == leader) wbase = atomicAdd(&cntL, wcnt);
                    wbase = __shfl(wbase, leader);
                    if (take) {
                        unsigned pos = wbase + (unsigned)__popcll(m & ((1ull << lane) - 1ull));
                        s[pos] = key;
                    }
                }
            }
            __syncthreads();
            n2 = cntL;
        }
    }

    if (fb) {
        // ---- exact fallback: in-block 3-pass re-scan of this batch's channels
        __syncthreads();
        for (int i = t; i < NBINS; i += 256) lh[i] = 0u;
        shC[t] = 0u;
        if (t == 0) { cntL = 0u; T1s = 0u; cntHiS = 0u; Us = 0u; }
        __syncthreads();

        // pass 1: 1024-bin hist over all local maxima with f > 0.01
        for (int cc = 0; cc < C_; cc++) {
            const float4* im = (const float4*)(hm + ((size_t)b * C_ + cc) * HW_);
            nms_scan_channel(im, [&](float f, float m, int y, int x) {
                bool hit = (f > 0.01f && f >= m);
                unsigned bin = 0u;
                if (hit) {
                    bin = (__float_as_uint(f) >> 16) - BIN_BASE;
                    if (bin > NBINS - 1) bin = NBINS - 1;
                }
                hist_add(lh, hit, bin, lane);
            });
        }
        find_suffix_thresh(lh, seg, &T1s, &cntHiS);
        unsigned T1 = T1s, cntHi = cntHiS;

        // pass 2: collect bin>T1 keys; sub-hist bits[15:8] for bin==T1
        for (int cc = 0; cc < C_; cc++) {
            const float4* im = (const float4*)(hm + ((size_t)b * C_ + cc) * HW_);
            nms_scan_channel(im, [&](float f, float m, int y, int x) {
                if (f > 0.01f && f >= m) {
                    unsigned bits = __float_as_uint(f);
                    unsigned bin = (bits >> 16) - BIN_BASE;
                    if (bin > NBINS - 1) bin = NBINS - 1;
                    if (bin > T1) {
                        unsigned pos = atomicAdd(&cntL, 1u);
                        if (pos < SORTN) s[pos] = make_key(bits, cc, y, x);
                    } else if (bin == T1) {
                        atomicAdd(&shC[(bits >> 8) & 255u], 1u);
                    }
                }
            });
        }
        __syncthreads();
        sufC[t] = shC[t];
        __syncthreads();
        for (int d = 1; d < 256; d <<= 1) {
            unsigned add = (t + d < 256) ? sufC[t + d] : 0u;
            __syncthreads();
            sufC[t] += add;
            __syncthreads();
        }
        unsigned myS = cntHi + sufC[t];
        unsigned nxS = cntHi + ((t < 255) ? sufC[t + 1] : 0u);
        if (t == 0 && myS < 100u) Us = 0u;
        if (myS >= 100u && nxS < 100u) Us = (unsigned)t;
        __syncthreads();
        unsigned U = Us;

        // pass 3: collect bin==T1 && sub>=U keys
        for (int cc = 0; cc < C_; cc++) {
            const float4* im = (const float4*)(hm + ((size_t)b * C_ + cc) * HW_);
            nms_scan_channel(im, [&](float f, float m, int y, int x) {
                if (f > 0.01f && f >= m) {
                    unsigned bits = __float_as_uint(f);
                    unsigned bin = (bits >> 16) - BIN_BASE;
                    if (bin > NBINS - 1) bin = NBINS - 1;
                    if (bin == T1 && ((bits >> 8) & 255u) >= U) {
                        unsigned pos = atomicAdd(&cntL, 1u);
                        if (pos < SORTN) s[pos] = make_key(bits, cc, y, x);
                    }
                }
            });
        }
        __syncthreads();
        n2 = cntL;
    }
    if (n2 > SORTN) n2 = SORTN;

    // ---- rank selection: keys are unique (idx packed in low bits), so
    // rank = #{keys > mine} is a bijection onto [0, n2). Pad with 0 up to SN.
    unsigned SN = (n2 <= 256u) ? 256u : (unsigned)SORTN;
    for (unsigned i = n2 + t; i < SN; i += 256) s[i] = 0ull;
    __syncthreads();

    if (SN == 256u) {
        unsigned long long my = s[t];
        unsigned rank = 0u;
        #pragma unroll 8
        for (int i = 0; i < 256; i++) rank += (s[i] > my) ? 1u : 0u;
        if ((unsigned)t < n2 && rank < 100u)
            decode_write(my, rank, b, offset, wh, out);
    } else {
        unsigned long long my[4];
        unsigned rk[4] = {0u, 0u, 0u, 0u};
        #pragma unroll
        for (int q = 0; q < 4; q++) my[q] = s[t + 256 * q];
        for (int i = 0; i < SORTN; i += 4) {
            unsigned long long v0 = s[i], v1 = s[i + 1], v2 = s[i + 2], v3 = s[i + 3];
            #pragma unroll
            for (int q = 0; q < 4; q++) {
                rk[q] += (v0 > my[q]) ? 1u : 0u;
                rk[q] += (v1 > my[q]) ? 1u : 0u;
                rk[q] += (v2 > my[q]) ? 1u : 0u;
                rk[q] += (v3 > my[q]) ? 1u : 0u;
            }
        }
        #pragma unroll
        for (int q = 0; q < 4; q++) {
            unsigned pos = (unsigned)t + 256u * q;
            if (pos < n2 && rk[q] < 100u)
                decode_write(my[q], rk[q], b, offset, wh, out);
        }
    }

    // default rows for r in [n2, 100)  (fallback-only case: total < 100)
    if ((unsigned)t >= n2 && t < 100) {
        int o = b * 100 + t;
        out[o]        = -1.0f;
        out[1600 + o] = -1.0f;
        float* bb = out + 3200 + o * 4;
        bb[0] = -4.0f; bb[1] = -4.0f; bb[2] = -4.0f; bb[3] = -4.0f;
    }
}

// ---------------------------------------------------------------------------
extern "C" void kernel_launch(void* const* d_in, const int* in_sizes, int n_in,
                              void* d_out, int out_size, void* d_ws, size_t ws_size,
                              hipStream_t stream) {
    const float* heatmap = (const float*)d_in[0];
    const float* offset  = (const float*)d_in[1];
    const float* wh      = (const float*)d_in[2];
    float* out = (float*)d_out;

    char* ws = (char*)d_ws;
    unsigned* chCnt = (unsigned*)(ws + WS_CC_OFF);
    unsigned* done  = (unsigned*)(ws + WS_DONE_OFF);
    unsigned long long* buf = (unsigned long long*)(ws + WS_BUF_OFF);

    // ws is poisoned every iteration -> done[] counters must be cleared.
    // memset node is graph-capture-safe (stream-ordered, 64 B).
    hipMemsetAsync(done, 0, B_ * sizeof(unsigned), stream);
    nms_topk_fused<<<dim3(B_ * C_), dim3(256), 0, stream>>>(
        heatmap, chCnt, buf, done, offset, wh, out);
}

// Round 4
// 140.513 us; speedup vs baseline: 1.4326x; 1.4326x over previous
//
#include <hip/hip_runtime.h>
#include <stdint.h>

// Problem constants
#define B_    16
#define C_    80
#define H_    128
#define W_    128
#define HW_   16384        // H_*W_
#define NBINS 1024
#define BIN_BASE 0x3C00u   // float bits>>16 lower bound for scores > ~0.0078
#define SORTN 1024
// Eager pre-filter: 0.9992675781f. Per-batch NMS+thr survivors ~958 (>=100 w/
// 27-sigma margin on uniform data); per-channel ~12 (cap 64 untouchable). Any
// violation -> exact fallback.
#define F1_BITS 0x3F7FD000u
#define CHCAP 64u          // per-channel candidate cap. MUST be 64 (>>6 / &63).
#define PADTOT (C_ * (int)CHCAP)   // 5120 padded slots per batch
#define NSLOT  20          // PADTOT / 256 slots per thread in K2
#define FSHIFT 5           // fine-hist shift: bin = (bits - F1_BITS) >> 5
#define FBINS 512          // logical 384 used ((0x3000>>5)=384); padded to 512

// ws layout (bytes) — NO zeroed state; everything written unconditionally:
//   chCnt : B_*C_*4 = 5120  @ 0
//   buf   : B_*C_*CHCAP*8 = 640KB @ 8192
// NOTE (round 3 lesson): do NOT fuse the two kernels with a last-block-done
// flag — the per-block agent-scope __threadfence forces an XCD-L2
// writeback/invalidate; 1280 of them serialized cost ~85 µs and evicted the
// L3-resident input (measured: fused kernel 110 µs even with warm cache,
// FETCH re-fetch 42 MB, VALUBusy 1.4%). The kernel boundary is ~3 µs. Keep it.
#define WS_CC_OFF  0
#define WS_BUF_OFF 8192

// Horizontal 3-max (incl. center) of a 4-wide strip, halo via wave shuffle.
// (fallback path only)
__device__ __forceinline__ float4 hmax3(float4 v, int srcL, int srcR, int tx) {
    float lft = __shfl(v.w, srcL);
    float rgt = __shfl(v.x, srcR);
    if (tx == 0)  lft = -1.f;
    if (tx == 31) rgt = -1.f;
    float4 h;
    h.x = fmaxf(v.x, fmaxf(lft, v.y));
    h.y = fmaxf(v.y, fmaxf(v.x, v.z));
    h.z = fmaxf(v.z, fmaxf(v.y, v.w));
    h.w = fmaxf(v.w, fmaxf(v.z, rgt));
    return h;
}

// Wave-aggregated LDS histogram add (degenerate same-bin case -> 1 atomic/wave).
__device__ __forceinline__ void hist_add(unsigned* lh, bool valid, unsigned bin,
                                         int lane) {
    unsigned long long vm = __ballot(valid);
    if (vm == 0ull) return;
    int leader = __ffsll((unsigned long long)vm) - 1;
    unsigned lbin = __shfl(bin, leader);
    unsigned long long sm = __ballot(valid && bin == lbin);
    if (sm == vm) {
        if (lane == leader) atomicAdd(&lh[lbin], (unsigned)__popcll(vm));
    } else if (valid) {
        atomicAdd(&lh[bin], 1u);
    }
}

__device__ __forceinline__ unsigned long long make_key(unsigned bits, int c,
                                                       int y, int x) {
    unsigned idx = ((unsigned)c << 14) | ((unsigned)y << 7) | (unsigned)x;
    return ((unsigned long long)bits << 32) |
           (unsigned long long)(0xFFFFFFFFu - idx);
}

// Rolling 3-row NMS scan of one 128x128 channel (fallback path only).
// emit(f, m3x3, y, x) invoked for ALL pixels (safe for wave-ballot inside).
template <typename EmitFn>
__device__ __forceinline__ void nms_scan_channel(const float4* __restrict__ img,
                                                 EmitFn emit) {
    int tx = threadIdx.x & 31;
    int ty = threadIdx.x >> 5;
    int y0 = ty << 4;
    int lane = threadIdx.x & 63;
    int srcL = (lane > 0) ? lane - 1 : 0;
    int srcR = (lane < 63) ? lane + 1 : 63;
    const float4 neg1 = make_float4(-1.f, -1.f, -1.f, -1.f);

    float4 r0 = (y0 > 0) ? img[(y0 - 1) * 32 + tx] : neg1;
    float4 hprev = hmax3(r0, srcL, srcR, tx);
    float4 vcur = img[y0 * 32 + tx];
    float4 hcur = hmax3(vcur, srcL, srcR, tx);

    #pragma unroll 4
    for (int i = 0; i < 16; i++) {
        int y = y0 + i;
        float4 vn = (y + 1 < H_) ? img[(y + 1) * 32 + tx] : neg1;
        float4 hnext = hmax3(vn, srcL, srcR, tx);
        float mm[4];
        mm[0] = fmaxf(hprev.x, fmaxf(hcur.x, hnext.x));
        mm[1] = fmaxf(hprev.y, fmaxf(hcur.y, hnext.y));
        mm[2] = fmaxf(hprev.z, fmaxf(hcur.z, hnext.z));
        mm[3] = fmaxf(hprev.w, fmaxf(hcur.w, hnext.w));
        float vv[4] = {vcur.x, vcur.y, vcur.z, vcur.w};
        #pragma unroll
        for (int j = 0; j < 4; j++) emit(vv[j], mm[j], y, tx * 4 + j);
        hprev = hcur; hcur = hnext; vcur = vn;
    }
}

// 1024-bin suffix threshold (fallback): T = smallest bin with suffix >= 100
// (0 if total < 100); cntHi = count strictly above T.
__device__ __forceinline__ void find_suffix_thresh(const unsigned* __restrict__ h,
                                                   unsigned* __restrict__ seg,
                                                   unsigned* Tout,
                                                   unsigned* cntHiOut) {
    __syncthreads();
    int t = threadIdx.x;
    int base = t * 4;
    unsigned h0 = h[base], h1 = h[base + 1], h2 = h[base + 2], h3 = h[base + 3];
    seg[t] = h0 + h1 + h2 + h3;
    __syncthreads();
    for (int d = 1; d < 256; d <<= 1) {
        unsigned add = (t + d < 256) ? seg[t + d] : 0u;
        __syncthreads();
        seg[t] += add;
        __syncthreads();
    }
    unsigned mySuf = seg[t];
    unsigned nextSuf = (t < 255) ? seg[t + 1] : 0u;
    if (t == 0 && mySuf < 100u) { *Tout = 0u; *cntHiOut = mySuf - h0; }
    if (mySuf >= 100u && nextSuf < 100u) {
        unsigned cum = nextSuf;
        unsigned hv[4] = {h0, h1, h2, h3};
        for (int i = 3; i >= 0; i--) {
            cum += hv[i];
            if (cum >= 100u) { *Tout = (unsigned)(base + i); *cntHiOut = cum - hv[i]; break; }
        }
    }
    __syncthreads();
}

// ---------------------------------------------------------------------------
// K1: threshold-first eager scan with an EXPLICIT 16-deep load pipeline.
// All 16 row loads (256 B/thread) are issued before any use -> 16 loads in
// flight per thread, HBM-throughput-bound. Pre-filter is pure integer VALU
// (~6 ops/row) building a 16-bit row mask; survivors (~12 per 16384-pixel
// channel) take a divergent while-loop that re-reads the 3x3 neighborhood
// from L1. No runtime indexing of R[] (would spill to scratch).
// grid: B_*C_ = 1280 blocks of 256 (thread = 16 rows x 4 cols).
// ---------------------------------------------------------------------------
__global__ __launch_bounds__(256) void nms_eager(const float* __restrict__ hm,
                                                 unsigned* __restrict__ chCnt,
                                                 unsigned long long* __restrict__ buf) {
    __shared__ unsigned lcnt;
    if (threadIdx.x == 0) lcnt = 0u;
    __syncthreads();

    int bc = blockIdx.x;         // b*C_ + c
    int c  = bc % C_;
    int tx = threadIdx.x & 31;
    int ty = threadIdx.x >> 5;
    int y0 = ty << 4;
    const float* base = hm + (size_t)bc * HW_;
    const float4* img = (const float4*)base;
    unsigned long long* myseg = buf + (size_t)bc * CHCAP;

    // Phase 1: issue all 16 independent row loads (compiler batches vmcnt).
    float4 R[16];
    #pragma unroll
    for (int k = 0; k < 16; k++) R[k] = img[(y0 + k) * 32 + tx];

    // Phase 2: integer pre-filter -> 16-bit row mask (floats are positive, so
    // uint compare == float compare).
    unsigned mask = 0u;
    #pragma unroll
    for (int k = 0; k < 16; k++) {
        unsigned a = __float_as_uint(R[k].x), b = __float_as_uint(R[k].y);
        unsigned cc2 = __float_as_uint(R[k].z), d = __float_as_uint(R[k].w);
        unsigned m0 = a > b ? a : b;
        unsigned m1 = cc2 > d ? cc2 : d;
        unsigned mx = m0 > m1 ? m0 : m1;
        mask |= (mx >= F1_BITS ? 1u : 0u) << k;
    }

    // Phase 3: rare path (expected ~1-2 candidates per block).
    while (mask) {
        int k = __ffs(mask) - 1;
        mask &= mask - 1u;
        int y = y0 + k;
        float4 v = img[y * 32 + tx];       // L1-hot reload (no R[k] runtime idx)
        float vv[4] = {v.x, v.y, v.z, v.w};
        #pragma unroll
        for (int j = 0; j < 4; j++) {
            float f = vv[j];
            if (__float_as_uint(f) < F1_BITS) continue;
            int x = tx * 4 + j;
            bool xm = (x > 0), xp = (x < W_ - 1);
            float m = -1.f;
            if (y > 0) {
                const float* r = base + (y - 1) * W_;
                if (xm) m = fmaxf(m, r[x - 1]);
                m = fmaxf(m, r[x]);
                if (xp) m = fmaxf(m, r[x + 1]);
            }
            {
                const float* r = base + y * W_;
                if (xm) m = fmaxf(m, r[x - 1]);
                if (xp) m = fmaxf(m, r[x + 1]);
            }
            if (y < H_ - 1) {
                const float* r = base + (y + 1) * W_;
                if (xm) m = fmaxf(m, r[x - 1]);
                m = fmaxf(m, r[x]);
                if (xp) m = fmaxf(m, r[x + 1]);
            }
            if (f >= m) {
                unsigned pos = atomicAdd(&lcnt, 1u);
                if (pos < CHCAP)
                    myseg[pos] = make_key(__float_as_uint(f), c, y, x);
            }
        }
    }

    __syncthreads();
    if (threadIdx.x == 0) chCnt[bc] = lcnt;
}

// decode one key into output row r of batch b
__device__ __forceinline__ void decode_write(unsigned long long key, unsigned r,
                                             int b,
                                             const float* __restrict__ offset,
                                             const float* __restrict__ wh,
                                             float* __restrict__ out) {
    unsigned bits = (unsigned)(key >> 32);
    unsigned idx  = 0xFFFFFFFFu - (unsigned)(key & 0xFFFFFFFFu);
    int cc = (int)(idx >> 14);
    int sp = (int)(idx & 16383u);
    int y  = sp >> 7;
    int x  = sp & 127;
    const float* offb = offset + (size_t)b * 2 * HW_;
    const float* whb  = wh + (size_t)b * 2 * HW_;
    float ox = offb[sp], oy = offb[HW_ + sp];
    float wwv = whb[sp], hh = whb[HW_ + sp];
    float cx = (float)x + ox;
    float cy = (float)y + oy;
    int o = b * 100 + (int)r;
    out[o]        = (float)cc;
    out[1600 + o] = __uint_as_float(bits);
    float* bb = out + 3200 + o * 4;
    bb[0] = (cx - wwv * 0.5f) * 4.0f;
    bb[1] = (cy - hh * 0.5f) * 4.0f;
    bb[2] = (cx + wwv * 0.5f) * 4.0f;
    bb[3] = (cy + hh * 0.5f) * 4.0f;
}

// ---------------------------------------------------------------------------
// K2: per-batch top-100, REGISTER-RESIDENT fast path.
// Each thread loads its 20 slots of the padded candidate buffer into
// registers UP FRONT (one batched vmcnt wait instead of 20 serialized
// ~500-900cy global-load latencies), builds the 384-fine-bin hist, suffix-
// scans it with a 2-barrier shuffle scan (was 16 barriers), then compacts the
// bin>=U2 keys STRAIGHT FROM REGISTERS into the select buffer (the 16KB LDS
// stash pass of the previous version is gone). Guards (channel overflow /
// <100 total / takeCnt > SORTN) -> exact in-block 3-pass re-scan. Tail:
// rank-selection (keys unique -> rank = #{keys > mine}) + fused decode.
// grid: B_ blocks of 256.
// ---------------------------------------------------------------------------
__global__ __launch_bounds__(256) void topk_decode(const float* __restrict__ hm,
                                                   const unsigned long long* __restrict__ buf,
                                                   const unsigned* __restrict__ chCnt,
                                                   const float* __restrict__ offset,
                                                   const float* __restrict__ wh,
                                                   float* __restrict__ out) {
    int b = blockIdx.x;
    int t = threadIdx.x;
    int lane = t & 63;
    __shared__ unsigned long long s[SORTN];   // 8 KB select buffer
    __shared__ unsigned lh[NBINS];            // fast: [0..FBINS); fb: all 1024
    __shared__ unsigned seg[256];
    __shared__ unsigned shC[256];
    __shared__ unsigned sufC[256];
    __shared__ unsigned scnt[C_];
    __shared__ unsigned wtot[4];
    __shared__ unsigned rawTotS, ovfS, U2s, takeS, T1s, cntHiS, Us, cntL;

    if (t == 0) { rawTotS = 0u; ovfS = 0u; cntL = 0u;
                  U2s = 0u; takeS = 0u; T1s = 0u; cntHiS = 0u; Us = 0u; }
    lh[t] = 0u; lh[t + 256] = 0u;             // fast path uses FBINS=512
    __syncthreads();
    if (t < C_) {
        unsigned r = chCnt[b * C_ + t];
        atomicAdd(&rawTotS, r);
        if (r > CHCAP) atomicOr(&ovfS, 1u);
        scnt[t] = r > CHCAP ? CHCAP : r;
    }
    __syncthreads();
    bool fb = (rawTotS < 100u) || (ovfS != 0u);

    const unsigned long long* bufb = buf + (size_t)b * C_ * CHCAP;
    unsigned n2 = 0u;

    if (!fb) {
        // ---- batched load: ALL slots into registers (incl. poison of
        // invalid slots — only consumed under vmask). 20 loads in flight.
        unsigned long long kv[NSLOT];
        #pragma unroll
        for (int q = 0; q < NSLOT; q++) kv[q] = bufb[q * 256u + (unsigned)t];

        // validity mask + fine hist (scnt[i>>6] is wave-uniform -> broadcast)
        unsigned vmask = 0u;
        #pragma unroll
        for (int q = 0; q < NSLOT; q++) {
            unsigned i = q * 256u + (unsigned)t;
            if ((i & (CHCAP - 1u)) < scnt[i >> 6]) {
                vmask |= 1u << q;
                unsigned bin = ((unsigned)(kv[q] >> 32) - F1_BITS) >> FSHIFT;
                if (bin > FBINS - 1u) bin = FBINS - 1u;
                atomicAdd(&lh[bin], 1u);
            }
        }
        __syncthreads();

        // ---- 2-barrier suffix scan over FBINS (2 bins/thread):
        // intra-wave shuffle suffix scan + cross-wave totals.
        unsigned g0 = lh[t * 2], g1 = lh[t * 2 + 1];
        unsigned segv = g0 + g1;
        unsigned v = segv;
        #pragma unroll
        for (int d = 1; d < 64; d <<= 1) {
            unsigned o = __shfl_down(v, d);
            if (lane + d < 64) v += o;
        }
        if (lane == 0) wtot[t >> 6] = v;      // wave total = suffix from lane 0
        __syncthreads();
        unsigned tail = 0u;
        for (int ww = (t >> 6) + 1; ww < 4; ww++) tail += wtot[ww];
        unsigned mySuf = v + tail;            // = sum of seg[t..255]
        unsigned nextSuf = mySuf - segv;      // = sum of seg[t+1..255]
        if (mySuf >= 100u && nextSuf < 100u) {   // exists since rawTot >= 100
            unsigned cum1 = nextSuf + g1;
            if (cum1 >= 100u) { U2s = (unsigned)(t * 2 + 1); takeS = cum1; }
            else              { U2s = (unsigned)(t * 2);     takeS = cum1 + g0; }
        }
        __syncthreads();
        unsigned U2 = U2s, takeCnt = takeS;
        if (takeCnt > SORTN) fb = true;          // massive tie block
        if (!fb) {
            // ---- compact straight from registers (keys with fine-bin >= U2)
            #pragma unroll
            for (int q = 0; q < NSLOT; q++) {
                unsigned long long key = kv[q];
                bool take = false;
                if (vmask & (1u << q)) {
                    unsigned bin = ((unsigned)(key >> 32) - F1_BITS) >> FSHIFT;
                    if (bin > FBINS - 1u) bin = FBINS - 1u;
                    take = (bin >= U2);
                }
                unsigned long long m = __ballot(take);
                if (m != 0ull) {
                    int leader = __ffsll((unsigned long long)m) - 1;
                    unsigned wcnt = (unsigned)__popcll(m);
                    unsigned wbase = 0u;
                    if (lane == leader) wbase = atomicAdd(&cntL, wcnt);
                    wbase = __shfl(wbase, leader);
                    if (take) {
                        unsigned pos = wbase + (unsigned)__popcll(m & ((1ull << lane) - 1ull));
                        s[pos] = key;          // pos < takeCnt <= SORTN
                    }
                }
            }
            __syncthreads();
            n2 = cntL;
        }
    }

    if (fb) {
        // ---- exact fallback: in-block 3-pass re-scan of this batch's channels
        __syncthreads();
        for (int i = t; i < NBINS; i += 256) lh[i] = 0u;
        shC[t] = 0u;
        if (t == 0) { cntL = 0u; T1s = 0u; cntHiS = 0u; Us = 0u; }
        __syncthreads();

        // pass 1: 1024-bin hist over all local maxima with f > 0.01
        for (int cc = 0; cc < C_; cc++) {
            const float4* im = (const float4*)(hm + ((size_t)b * C_ + cc) * HW_);
            nms_scan_channel(im, [&](float f, float m, int y, int x) {
                bool hit = (f > 0.01f && f >= m);
                unsigned bin = 0u;
                if (hit) {
                    bin = (__float_as_uint(f) >> 16) - BIN_BASE;
                    if (bin > NBINS - 1) bin = NBINS - 1;
                }
                hist_add(lh, hit, bin, lane);
            });
        }
        find_suffix_thresh(lh, seg, &T1s, &cntHiS);
        unsigned T1 = T1s, cntHi = cntHiS;

        // pass 2: collect bin>T1 keys; sub-hist bits[15:8] for bin==T1
        for (int cc = 0; cc < C_; cc++) {
            const float4* im = (const float4*)(hm + ((size_t)b * C_ + cc) * HW_);
            nms_scan_channel(im, [&](float f, float m, int y, int x) {
                if (f > 0.01f && f >= m) {
                    unsigned bits = __float_as_uint(f);
                    unsigned bin = (bits >> 16) - BIN_BASE;
                    if (bin > NBINS - 1) bin = NBINS - 1;
                    if (bin > T1) {
                        unsigned pos = atomicAdd(&cntL, 1u);
                        if (pos < SORTN) s[pos] = make_key(bits, cc, y, x);
                    } else if (bin == T1) {
                        atomicAdd(&shC[(bits >> 8) & 255u], 1u);
                    }
                }
            });
        }
        __syncthreads();
        sufC[t] = shC[t];
        __syncthreads();
        for (int d = 1; d < 256; d <<= 1) {
            unsigned add = (t + d < 256) ? sufC[t + d] : 0u;
            __syncthreads();
            sufC[t] += add;
            __syncthreads();
        }
        unsigned myS = cntHi + sufC[t];
        unsigned nxS = cntHi + ((t < 255) ? sufC[t + 1] : 0u);
        if (t == 0 && myS < 100u) Us = 0u;
        if (myS >= 100u && nxS < 100u) Us = (unsigned)t;
        __syncthreads();
        unsigned U = Us;

        // pass 3: collect bin==T1 && sub>=U keys
        for (int cc = 0; cc < C_; cc++) {
            const float4* im = (const float4*)(hm + ((size_t)b * C_ + cc) * HW_);
            nms_scan_channel(im, [&](float f, float m, int y, int x) {
                if (f > 0.01f && f >= m) {
                    unsigned bits = __float_as_uint(f);
                    unsigned bin = (bits >> 16) - BIN_BASE;
                    if (bin > NBINS - 1) bin = NBINS - 1;
                    if (bin == T1 && ((bits >> 8) & 255u) >= U) {
                        unsigned pos = atomicAdd(&cntL, 1u);
                        if (pos < SORTN) s[pos] = make_key(bits, cc, y, x);
                    }
                }
            });
        }
        __syncthreads();
        n2 = cntL;
    }
    if (n2 > SORTN) n2 = SORTN;

    // ---- rank selection: keys are unique (idx packed in low bits), so
    // rank = #{keys > mine} is a bijection onto [0, n2). Pad with 0 up to SN;
    // 1 barrier total. Order-independent -> output identical regardless of
    // compaction order.
    unsigned SN = (n2 <= 256u) ? 256u : (unsigned)SORTN;
    for (unsigned i = n2 + t; i < SN; i += 256) s[i] = 0ull;
    __syncthreads();

    if (SN == 256u) {
        unsigned long long my = s[t];
        unsigned rank = 0u;
        #pragma unroll 8
        for (int i = 0; i < 256; i++) rank += (s[i] > my) ? 1u : 0u;
        if ((unsigned)t < n2 && rank < 100u)
            decode_write(my, rank, b, offset, wh, out);
    } else {
        unsigned long long my[4];
        unsigned rk[4] = {0u, 0u, 0u, 0u};
        #pragma unroll
        for (int q = 0; q < 4; q++) my[q] = s[t + 256 * q];
        for (int i = 0; i < SORTN; i += 4) {
            unsigned long long v0 = s[i], v1 = s[i + 1], v2 = s[i + 2], v3 = s[i + 3];
            #pragma unroll
            for (int q = 0; q < 4; q++) {
                rk[q] += (v0 > my[q]) ? 1u : 0u;
                rk[q] += (v1 > my[q]) ? 1u : 0u;
                rk[q] += (v2 > my[q]) ? 1u : 0u;
                rk[q] += (v3 > my[q]) ? 1u : 0u;
            }
        }
        #pragma unroll
        for (int q = 0; q < 4; q++) {
            unsigned pos = (unsigned)t + 256u * q;
            if (pos < n2 && rk[q] < 100u)
                decode_write(my[q], rk[q], b, offset, wh, out);
        }
    }

    // default rows for r in [n2, 100)  (fallback-only case: total < 100)
    if ((unsigned)t >= n2 && t < 100) {
        int o = b * 100 + t;
        out[o]        = -1.0f;
        out[1600 + o] = -1.0f;
        float* bb = out + 3200 + o * 4;
        bb[0] = -4.0f; bb[1] = -4.0f; bb[2] = -4.0f; bb[3] = -4.0f;
    }
}

// ---------------------------------------------------------------------------
extern "C" void kernel_launch(void* const* d_in, const int* in_sizes, int n_in,
                              void* d_out, int out_size, void* d_ws, size_t ws_size,
                              hipStream_t stream) {
    const float* heatmap = (const float*)d_in[0];
    const float* offset  = (const float*)d_in[1];
    const float* wh      = (const float*)d_in[2];
    float* out = (float*)d_out;

    char* ws = (char*)d_ws;
    unsigned* chCnt = (unsigned*)(ws + WS_CC_OFF);
    unsigned long long* buf = (unsigned long long*)(ws + WS_BUF_OFF);

    nms_eager<<<dim3(B_ * C_), dim3(256), 0, stream>>>(heatmap, chCnt, buf);
    topk_decode<<<dim3(B_), dim3(256), 0, stream>>>(heatmap, buf, chCnt,
                                                    offset, wh, out);
}